// Round 6
// baseline (1054.765 us; speedup 1.0000x reference)
//
#include <hip/hip_runtime.h>
#include <hip/hip_cooperative_groups.h>
#include <hip/hip_bf16.h>
#include <cstdint>
#include <cstddef>

namespace cg = cooperative_groups;

#define IN_FEATS 256
#define NUM_HEADS 8
#define HD 512
#define CH 32
#define NBLK 768
#define NTHR 256
#define QSC (NBLK / NTHR)   // 3 scan items per thread in block0

typedef __attribute__((ext_vector_type(8))) short bf16x8;
typedef __attribute__((ext_vector_type(4))) float f32x4;

struct Params {
    const float *W, *al, *ar, *feat, *adj;
    const int *src, *dst, *idxp;
    int *deg, *row_start, *cursor, *slot_src, *blocksum, *blockoff;
    float *wlr, *el, *er;
    unsigned short *Wt, *featb, *hb;
    float *out;
    int M, E;
};

__device__ inline unsigned short bf16_bits(float f) {
    unsigned x = __float_as_uint(f);
    x += 0x7fffu + ((x >> 16) & 1u);  // RNE
    return (unsigned short)(x >> 16);
}
__device__ inline unsigned pack_bf2(float a, float b) {
    return ((unsigned)bf16_bits(a)) | (((unsigned)bf16_bits(b)) << 16);
}

__global__ __launch_bounds__(NTHR, 4) void fused(Params p) {
    cg::grid_group grid = cg::this_grid();
    const int bid = blockIdx.x;
    const int t = threadIdx.x;
    const int M = p.M, E = p.E;
    __shared__ __align__(16) char smem[17472];

    // ======== P1: count histogram | wlr | Wt transpose ========
    for (int i = bid * NTHR + t; i < E; i += NBLK * NTHR)
        atomicAdd(&p.deg[p.dst[i]], 1);
    if (bid < 64) {
        // wlr[k][0..7]=W_k.attn_l per head, [8..15]=W_k.attn_r
        const int k = bid * 4 + (t >> 6);
        const int l = t & 63;
        float4 w0 = *(const float4*)(p.W + (size_t)k * HD + 8 * l);
        float4 w1 = *(const float4*)(p.W + (size_t)k * HD + 8 * l + 4);
        float4 a0 = *(const float4*)(p.al + 8 * l);
        float4 a1 = *(const float4*)(p.al + 8 * l + 4);
        float4 b0 = *(const float4*)(p.ar + 8 * l);
        float4 b1 = *(const float4*)(p.ar + 8 * l + 4);
        float pl = w0.x * a0.x + w0.y * a0.y + w0.z * a0.z + w0.w * a0.w +
                   w1.x * a1.x + w1.y * a1.y + w1.z * a1.z + w1.w * a1.w;
        float pr = w0.x * b0.x + w0.y * b0.y + w0.z * b0.z + w0.w * b0.w +
                   w1.x * b1.x + w1.y * b1.y + w1.z * b1.z + w1.w * b1.w;
#pragma unroll
        for (int off = 1; off < 8; off <<= 1) {
            pl += __shfl_xor(pl, off);
            pr += __shfl_xor(pr, off);
        }
        if ((l & 7) == 0) {
            p.wlr[k * 16 + (l >> 3)] = pl;
            p.wlr[k * 16 + 8 + (l >> 3)] = pr;
        }
    } else if (bid < 96) {
        // Wt[h][d][k] = bf16(W[k][h*64+d])
        float (*tile)[65] = (float(*)[65])smem;
        const int bb = bid - 64;
        const int h = bb >> 2;
        const int k0 = (bb & 3) * 64;
#pragma unroll 4
        for (int it = 0; it < 16; ++it) {
            int r = it * 4 + (t >> 6);
            int c = t & 63;
            tile[r][c] = p.W[(size_t)(k0 + r) * HD + h * 64 + c];
        }
        __syncthreads();
#pragma unroll 4
        for (int it = 0; it < 16; ++it) {
            int c = it * 4 + (t >> 6);
            int k = t & 63;
            p.Wt[((size_t)h * 64 + c) * IN_FEATS + k0 + k] = bf16_bits(tile[k][c]);
        }
    }
    __threadfence();
    grid.sync();

    // ======== P2a: per-block degree partial sums ========
    const int C2 = (M + NBLK - 1) / NBLK;   // 14 for M=10000 (<=16 required)
    const int beg = bid * C2;
    {
        int d = 0;
        if (t < C2 && beg + t < M) d = p.deg[beg + t];
#pragma unroll
        for (int off = 1; off < 16; off <<= 1) d += __shfl_xor(d, off, 16);
        if (t == 0) p.blocksum[bid] = d;
    }
    __threadfence();
    grid.sync();

    // ======== P2b: block0 scans partials | others do elr+featb ========
    if (bid == 0) {
        int* sm = (int*)smem;  // [0..3]=wave sums, [4..7]=wave offsets
        const int q = t * QSC;
        int v[QSC], incl[QSC];
        int run = 0;
#pragma unroll
        for (int i = 0; i < QSC; ++i) {
            v[i] = p.blocksum[q + i];
            run += v[i];
            incl[i] = run;
        }
        int inc = run;
        const int lane = t & 63, w = t >> 6;
#pragma unroll
        for (int off = 1; off < 64; off <<= 1) {
            int u = __shfl_up(inc, off);
            if (lane >= off) inc += u;
        }
        if (lane == 63) sm[w] = inc;
        __syncthreads();
        if (t == 0) {
            int r = 0;
#pragma unroll
            for (int i = 0; i < 4; ++i) { int vv = sm[i]; sm[4 + i] = r; r += vv; }
        }
        __syncthreads();
        int excl = sm[4 + w] + inc - run;
#pragma unroll
        for (int i = 0; i < QSC; ++i)
            p.blockoff[q + i] = excl + incl[i] - v[i];
    } else {
        float (*wle)[17] = (float(*)[17])smem;
        for (int i = t; i < 256 * 16; i += NTHR) wle[i >> 4][i & 15] = p.wlr[i];
        __syncthreads();
        const int lane = t & 63, wv = t >> 6;
        const int UNITS = (M + 3) / 4;
        for (int u = bid - 1; u < UNITS; u += NBLK - 1) {
            const int n = u * 4 + wv;
            if (n < M) {
                const float* frow = p.feat + (size_t)n * IN_FEATS;
                unsigned short* fbrow = p.featb + (size_t)n * IN_FEATS;
                float pv[16];
#pragma unroll
                for (int h = 0; h < 16; ++h) pv[h] = 0.f;
#pragma unroll
                for (int j = 0; j < 4; ++j) {
                    int k = lane + 64 * j;
                    float fv = frow[k];
                    fbrow[k] = bf16_bits(fv);
#pragma unroll
                    for (int h = 0; h < 16; ++h) pv[h] = fmaf(fv, wle[k][h], pv[h]);
                }
                float outv = 0.f;
#pragma unroll
                for (int h = 0; h < 16; ++h) {
                    float v = pv[h];
#pragma unroll
                    for (int off = 32; off; off >>= 1) v += __shfl_xor(v, off);
                    outv = (lane == h) ? v : outv;
                }
                if (lane < 8) p.el[n * NUM_HEADS + lane] = outv;
                else if (lane < 16) p.er[n * NUM_HEADS + lane - 8] = outv;
            }
        }
    }
    __threadfence();
    grid.sync();

    // ======== P2c: fill row_start / cursor ========
    if (beg < M && t < C2) {
        int i = beg + t;
        int d = (i < M) ? p.deg[i] : 0;
        int inc = d;
#pragma unroll
        for (int off = 1; off < 16; off <<= 1) {
            int u = __shfl_up(inc, off, 16);
            if (t >= off) inc += u;
        }
        int excl = p.blockoff[bid] + inc - d;
        if (i < M) { p.row_start[i] = excl; p.cursor[i] = excl; }
    }
    if (bid == 0 && t == 0) p.row_start[M] = E;
    __threadfence();
    grid.sync();

    // ======== P3: scatter edges into CSR ========
    for (int i = bid * NTHR + t; i < E; i += NBLK * NTHR) {
        int pos = atomicAdd(&p.cursor[p.dst[i]], 1);
        p.slot_src[pos] = p.src[i];
    }
    __threadfence();
    grid.sync();

    // ======== P4: per-node softmax + aggregation -> hb (bf16) ========
    {
        float (*w_lds)[CH][8] = (float(*)[CH][8])smem;        // 2048 B
        int (*s_lds)[CH] = (int(*)[CH])(smem + 2048);         // 256 B
        float* red = (float*)(smem + 2304);                   // 1024 B
        float* inv_s = (float*)(smem + 3328);                 // 32 B
        const int idx = p.idxp[0];
        const int pp = t >> 1, g = t & 1, hh = t & 7, j0 = t >> 3;
        for (int n = bid; n < M; n += NBLK) {
            const int row = p.row_start[n];
            const int cnt = p.row_start[n + 1] - row;
            if (cnt == 0) {
#pragma unroll
                for (int h = 0; h < 4; ++h)
                    *(unsigned*)&p.hb[(size_t)n * 2048 + (4 * g + h) * 256 + 2 * pp] = 0u;
                continue;
            }
            const float er_hh = p.er[n * NUM_HEADS + hh];
            const float* adj_col = p.adj + (size_t)idx * M + (n + idx);
            __syncthreads();  // close previous node's LDS usage
            float ssum = 0.f;
            float acc[8] = {0.f, 0.f, 0.f, 0.f, 0.f, 0.f, 0.f, 0.f};
            int s_r = 0;
            float w_r = 0.f;
            // stage chunk 0
            if (j0 < cnt) {
                s_r = p.slot_src[row + j0];
                float e = p.el[s_r * NUM_HEADS + hh] + er_hh;
                e = (e > 0.f) ? e : 0.2f * e;
                float pe = __expf(e);
                ssum += pe;
                w_r = pe * adj_col[(size_t)s_r * M];
                w_lds[0][j0][hh] = w_r;
                if (hh == 0) s_lds[0][j0] = s_r;
            }
            __syncthreads();
            int buf = 0;
            for (int base = 0; base < cnt; base += CH) {
                const bool more = (base + CH) < cnt;
                if (more) {
                    int j = base + CH + j0;
                    if (j < cnt) {
                        s_r = p.slot_src[row + j];
                        float e = p.el[s_r * NUM_HEADS + hh] + er_hh;
                        e = (e > 0.f) ? e : 0.2f * e;
                        float pe = __expf(e);
                        ssum += pe;
                        w_r = pe * adj_col[(size_t)s_r * M];
                    }
                }
                int c = min(CH, cnt - base);
                const int* srow = &s_lds[buf][0];
                const float* wrow = &w_lds[buf][0][0];
#pragma unroll 4
                for (int jj = 0; jj < c; ++jj) {
                    int s = srow[jj];
                    unsigned u = *(const unsigned*)(p.featb + (size_t)s * IN_FEATS + 2 * pp);
                    float fx = __uint_as_float((u & 0xffffu) << 16);
                    float fy = __uint_as_float(u & 0xffff0000u);
                    float4 w = *(const float4*)&wrow[jj * 8 + 4 * g];
                    acc[0] = fmaf(w.x, fx, acc[0]);
                    acc[1] = fmaf(w.y, fx, acc[1]);
                    acc[2] = fmaf(w.z, fx, acc[2]);
                    acc[3] = fmaf(w.w, fx, acc[3]);
                    acc[4] = fmaf(w.x, fy, acc[4]);
                    acc[5] = fmaf(w.y, fy, acc[5]);
                    acc[6] = fmaf(w.z, fy, acc[6]);
                    acc[7] = fmaf(w.w, fy, acc[7]);
                }
                if (more) {
                    int j = base + CH + j0;
                    if (j < cnt) {
                        w_lds[buf ^ 1][j0][hh] = w_r;
                        if (hh == 0) s_lds[buf ^ 1][j0] = s_r;
                    }
                    __syncthreads();
                    buf ^= 1;
                }
            }
            red[t] = ssum;
            __syncthreads();
#pragma unroll
            for (int off = 128; off >= 8; off >>= 1) {
                if (t < off) red[t] += red[t + off];
                __syncthreads();
            }
            if (t < 8) inv_s[t] = 1.f / red[t];
            __syncthreads();
#pragma unroll
            for (int h = 0; h < 4; ++h) {
                float inv = inv_s[4 * g + h];
                unsigned pk = pack_bf2(acc[h] * inv, acc[4 + h] * inv);
                *(unsigned*)&p.hb[(size_t)n * 2048 + (4 * g + h) * 256 + 2 * pp] = pk;
            }
        }
    }
    __threadfence();
    grid.sync();

    // ======== P5: out[n, h*64+d] = sum_k hb[n,h,k] * Wt[h,d,k] (bf16 MFMA) ========
    {
        const int NBX = (M + 63) / 64;
        const int lane = t & 63, wv = t >> 6;
        const int r = lane & 15;
        const int kg = lane >> 4;
        for (int id = bid; id < NBX * NUM_HEADS; id += NBLK) {
            const int bx = id % NBX;
            const int by = id / NBX;
            const int n0 = bx * 64 + wv * 16;
            const int arow = min(n0 + r, M - 1);
            const short* aptr = (const short*)p.hb + (size_t)arow * 2048 + by * IN_FEATS + kg * 8;
            const short* bptr = (const short*)p.Wt + ((size_t)by * 64 + r) * IN_FEATS + kg * 8;
            f32x4 acc4[4];
#pragma unroll
            for (int c = 0; c < 4; ++c) acc4[c] = (f32x4){0.f, 0.f, 0.f, 0.f};
#pragma unroll
            for (int kk = 0; kk < IN_FEATS; kk += 32) {
                bf16x8 a = *(const bf16x8*)(aptr + kk);
#pragma unroll
                for (int c = 0; c < 4; ++c) {
                    bf16x8 b = *(const bf16x8*)(bptr + (size_t)c * 16 * IN_FEATS + kk);
                    acc4[c] = __builtin_amdgcn_mfma_f32_16x16x32_bf16(a, b, acc4[c], 0, 0, 0);
                }
            }
            const int orow0 = n0 + kg * 4;
#pragma unroll
            for (int c = 0; c < 4; ++c) {
#pragma unroll
                for (int i = 0; i < 4; ++i) {
                    int rr = orow0 + i;
                    if (rr < M) p.out[(size_t)rr * HD + by * 64 + c * 16 + r] = acc4[c][i];
                }
            }
        }
    }
}

// ---------------- launch ----------------

extern "C" void kernel_launch(void* const* d_in, const int* in_sizes, int n_in,
                              void* d_out, int out_size, void* d_ws, size_t ws_size,
                              hipStream_t stream) {
    const int M = in_sizes[0] / IN_FEATS;  // 10000
    const int E = in_sizes[5];             // 320000

    char* ws = (char*)d_ws;
    size_t off = 0;
    auto alloc = [&](size_t bytes) -> void* {
        off = (off + 255) & ~(size_t)255;
        void* pp = ws + off;
        off += bytes;
        return pp;
    };
    unsigned short* hbuf  = (unsigned short*)alloc((size_t)M * 2048 * sizeof(short));
    unsigned short* featb = (unsigned short*)alloc((size_t)M * IN_FEATS * sizeof(short));
    unsigned short* Wt    = (unsigned short*)alloc((size_t)HD * IN_FEATS * sizeof(short));
    float* wlr       = (float*)alloc((size_t)IN_FEATS * 16 * sizeof(float));
    float* el        = (float*)alloc((size_t)M * NUM_HEADS * sizeof(float));
    float* er        = (float*)alloc((size_t)M * NUM_HEADS * sizeof(float));
    int* deg         = (int*)alloc((size_t)M * sizeof(int));
    int* row_start   = (int*)alloc((size_t)(M + 1) * sizeof(int));
    int* cursor      = (int*)alloc((size_t)M * sizeof(int));
    int* slot_src    = (int*)alloc((size_t)E * sizeof(int));
    int* blocksum    = (int*)alloc((size_t)NBLK * sizeof(int));
    int* blockoff    = (int*)alloc((size_t)NBLK * sizeof(int));

    hipMemsetAsync(deg, 0, (size_t)M * sizeof(int), stream);

    Params prm;
    prm.W = (const float*)d_in[1];
    prm.al = (const float*)d_in[2];
    prm.ar = (const float*)d_in[3];
    prm.feat = (const float*)d_in[0];
    prm.adj = (const float*)d_in[4];
    prm.src = (const int*)d_in[5];
    prm.dst = (const int*)d_in[6];
    prm.idxp = (const int*)d_in[7];
    prm.deg = deg;
    prm.row_start = row_start;
    prm.cursor = cursor;
    prm.slot_src = slot_src;
    prm.blocksum = blocksum;
    prm.blockoff = blockoff;
    prm.wlr = wlr;
    prm.el = el;
    prm.er = er;
    prm.Wt = Wt;
    prm.featb = featb;
    prm.hb = hbuf;
    prm.out = (float*)d_out;
    prm.M = M;
    prm.E = E;

    void* kargs[] = {&prm};
    hipLaunchCooperativeKernel(fused, dim3(NBLK), dim3(NTHR), kargs, 0, stream);
}

// Round 7
// 168.635 us; speedup vs baseline: 6.2547x; 6.2547x over previous
//
#include <hip/hip_runtime.h>
#include <hip/hip_bf16.h>
#include <cstdint>
#include <cstddef>

#define N_NODES_C 10000
#define IN_FEATS 256
#define NUM_HEADS 8
#define HD 512   // NUM_HEADS*OUT_FEATS

typedef __attribute__((ext_vector_type(8))) short bf16x8;
typedef __attribute__((ext_vector_type(4))) float f32x4;

__device__ inline unsigned short bf16_bits(float f) {
    unsigned x = __float_as_uint(f);
    x += 0x7fffu + ((x >> 16) & 1u);  // RNE
    return (unsigned short)(x >> 16);
}
__device__ inline float bf16_to_f(unsigned short u) {
    return __uint_as_float(((unsigned)u) << 16);
}
__device__ inline unsigned short pack1(float a) { return bf16_bits(a); }

// ---------------- K1: count | Wt transpose | wlr  (block-range fused) ----------------

__global__ __launch_bounds__(256) void k1_kernel(const float* __restrict__ W,
                                                 const float* __restrict__ al,
                                                 const float* __restrict__ ar,
                                                 const int* __restrict__ dst,
                                                 int* __restrict__ deg,
                                                 float* __restrict__ wlr,
                                                 unsigned short* __restrict__ Wt,
                                                 int E, int nb_cnt) {
    const int b = blockIdx.x;
    const int t = threadIdx.x;
    if (b < nb_cnt) {
        int i = b * 256 + t;
        if (i < E) atomicAdd(&deg[dst[i]], 1);
        return;
    }
    if (b < nb_cnt + 32) {
        // Wt[h][d][k] = bf16(W[k][h*64+d])
        __shared__ float tile[64][65];
        const int bb = b - nb_cnt;
        const int h = bb >> 2;
        const int k0 = (bb & 3) * 64;
#pragma unroll 4
        for (int it = 0; it < 16; ++it) {
            int r = it * 4 + (t >> 6);
            int c = t & 63;
            tile[r][c] = W[(size_t)(k0 + r) * HD + h * 64 + c];
        }
        __syncthreads();
#pragma unroll 4
        for (int it = 0; it < 16; ++it) {
            int c = it * 4 + (t >> 6);
            int k = t & 63;
            Wt[((size_t)h * 64 + c) * IN_FEATS + k0 + k] = bf16_bits(tile[k][c]);
        }
        return;
    }
    // wlr[k][0..7]=W_k . attn_l (per head), [8..15]=W_k . attn_r
    const int k = (b - nb_cnt - 32) * 4 + (t >> 6);
    const int l = t & 63;
    float4 w0 = *(const float4*)(W + (size_t)k * HD + 8 * l);
    float4 w1 = *(const float4*)(W + (size_t)k * HD + 8 * l + 4);
    float4 a0 = *(const float4*)(al + 8 * l);
    float4 a1 = *(const float4*)(al + 8 * l + 4);
    float4 b0 = *(const float4*)(ar + 8 * l);
    float4 b1 = *(const float4*)(ar + 8 * l + 4);
    float pl = w0.x * a0.x + w0.y * a0.y + w0.z * a0.z + w0.w * a0.w +
               w1.x * a1.x + w1.y * a1.y + w1.z * a1.z + w1.w * a1.w;
    float pr = w0.x * b0.x + w0.y * b0.y + w0.z * b0.z + w0.w * b0.w +
               w1.x * b1.x + w1.y * b1.y + w1.z * b1.z + w1.w * b1.w;
#pragma unroll
    for (int off = 1; off < 8; off <<= 1) {
        pl += __shfl_xor(pl, off);
        pr += __shfl_xor(pr, off);
    }
    if ((l & 7) == 0) {
        wlr[k * 16 + (l >> 3)] = pl;
        wlr[k * 16 + 8 + (l >> 3)] = pr;
    }
}

// ---------------- scan ----------------

__global__ __launch_bounds__(1024) void scan_kernel(const int* __restrict__ deg,
                                                    int* __restrict__ row_start,
                                                    int* __restrict__ cursor, int N) {
    __shared__ int wsum[16];
    __shared__ int woff[16];
    const int t = threadIdx.x;
    const int C = (N + 1023) / 1024;
    const int beg = t * C;
    const int end = min(beg + C, N);
    int s = 0;
    for (int i = beg; i < end; ++i) s += deg[i];
    const int lane = t & 63, wv = t >> 6;
    int v = s;
#pragma unroll
    for (int off = 1; off < 64; off <<= 1) {
        int u = __shfl_up(v, off);
        if (lane >= off) v += u;
    }
    if (lane == 63) wsum[wv] = v;
    __syncthreads();
    if (t == 0) {
        int run = 0;
#pragma unroll
        for (int i = 0; i < 16; ++i) { woff[i] = run; run += wsum[i]; }
        row_start[N] = run;
    }
    __syncthreads();
    int run = woff[wv] + v - s;  // exclusive prefix
    for (int i = beg; i < end; ++i) {
        row_start[i] = run;
        cursor[i] = run;
        run += deg[i];
    }
}

// ---------------- K3: scatter | elr (+ featb bf16 copy)  (block-range fused) ----------------

__global__ __launch_bounds__(256) void k3_kernel(const int* __restrict__ src,
                                                 const int* __restrict__ dst,
                                                 int* __restrict__ cursor,
                                                 int* __restrict__ slot_src,
                                                 const float* __restrict__ feat,
                                                 const float* __restrict__ wlr,
                                                 float* __restrict__ el,
                                                 float* __restrict__ er,
                                                 unsigned short* __restrict__ featb,
                                                 int E, int M, int nb_sc) {
    const int b = blockIdx.x;
    const int t = threadIdx.x;
    if (b < nb_sc) {
        int i = b * 256 + t;
        if (i < E) {
            int p = atomicAdd(&cursor[dst[i]], 1);
            slot_src[p] = src[i];
        }
        return;
    }
    // elr: el/er = feat @ wlr ; featb = bf16(feat)
    __shared__ float wle[256][17];
    for (int i = t; i < 256 * 16; i += 256) wle[i >> 4][i & 15] = wlr[i];
    __syncthreads();
    const int lane = t & 63, wv = t >> 6;
    const int n = (b - nb_sc) * 4 + wv;
    if (n >= M) return;
    const float* frow = feat + (size_t)n * IN_FEATS;
    unsigned short* fbrow = featb + (size_t)n * IN_FEATS;
    float p[16];
#pragma unroll
    for (int h = 0; h < 16; ++h) p[h] = 0.f;
#pragma unroll
    for (int j = 0; j < 4; ++j) {
        int k = lane + 64 * j;
        float fv = frow[k];
        fbrow[k] = bf16_bits(fv);
#pragma unroll
        for (int h = 0; h < 16; ++h) p[h] = fmaf(fv, wle[k][h], p[h]);
    }
    float outv = 0.f;
#pragma unroll
    for (int h = 0; h < 16; ++h) {
        float v = p[h];
#pragma unroll
        for (int off = 32; off; off >>= 1) v += __shfl_xor(v, off);
        outv = (lane == h) ? v : outv;
    }
    if (lane < 8) el[n * NUM_HEADS + lane] = outv;
    else if (lane < 16) er[n * NUM_HEADS + lane - 8] = outv;
}

// ---------------- agg: one WAVE per node, no LDS, no syncthreads ----------------
// lane -> (j0 = lane>>3 edge slot, hh = lane&7 head) for staging;
// lane -> dims [4*lane .. 4*lane+3] x 8 heads for accumulation (32 VGPR acc).
// hb[n*2048 + h*256 + k] = (sum_j w_jh * featb[s_j][k]) / sum_j p_jh

__global__ __launch_bounds__(256, 6) void agg_kernel(
    const unsigned short* __restrict__ featb, const float* __restrict__ el,
    const float* __restrict__ er, const float* __restrict__ adj,
    const int* __restrict__ row_start, const int* __restrict__ slot_src,
    const int* __restrict__ idxp, unsigned short* __restrict__ hb, int M) {
    const int lane = threadIdx.x & 63;
    const int n = blockIdx.x * 4 + (threadIdx.x >> 6);
    if (n >= M) return;
    const int row = row_start[n];
    const int cnt = row_start[n + 1] - row;
    unsigned short* hrow = hb + (size_t)n * 2048 + lane * 4;
    if (cnt == 0) {
        ushort4 z = {0, 0, 0, 0};
#pragma unroll
        for (int h = 0; h < 8; ++h) *(ushort4*)(hrow + h * 256) = z;
        return;
    }
    const int idx = idxp[0];
    const int hh = lane & 7;
    const int j0 = lane >> 3;
    const float er_hh = er[n * NUM_HEADS + hh];
    const float* adj_base = adj + (size_t)idx * M + (n + idx);

    float ssum = 0.f;
    f32x4 acc[8];
#pragma unroll
    for (int h = 0; h < 8; ++h) acc[h] = (f32x4){0.f, 0.f, 0.f, 0.f};

    int s_r = 0;
    float w_r = 0.f;
    auto stage = [&](int base) {
        int j = base + j0;
        int s = 0;
        float w = 0.f;
        if (j < cnt) {
            s = slot_src[row + j];
            float e = el[s * NUM_HEADS + hh] + er_hh;
            e = (e > 0.f) ? e : 0.2f * e;
            float pe = __expf(e);
            ssum += pe;
            w = pe * adj_base[(size_t)s * M];
        }
        s_r = s;
        w_r = w;
    };

    stage(0);
    for (int base = 0; base < cnt; base += 8) {
        const int s_cur = s_r;
        const float w_cur = w_r;
        if (base + 8 < cnt) stage(base + 8);
#pragma unroll
        for (int jj = 0; jj < 8; ++jj) {
            int sj = __shfl(s_cur, jj * 8);
            ushort4 f4 = *(const ushort4*)(featb + (size_t)sj * IN_FEATS + lane * 4);
            float f0 = bf16_to_f(f4.x), f1 = bf16_to_f(f4.y);
            float f2 = bf16_to_f(f4.z), f3 = bf16_to_f(f4.w);
#pragma unroll
            for (int h = 0; h < 8; ++h) {
                float wjh = __shfl(w_cur, jj * 8 + h);
                acc[h][0] = fmaf(wjh, f0, acc[h][0]);
                acc[h][1] = fmaf(wjh, f1, acc[h][1]);
                acc[h][2] = fmaf(wjh, f2, acc[h][2]);
                acc[h][3] = fmaf(wjh, f3, acc[h][3]);
            }
        }
    }
    // per-head sum: lanes with equal (lane&7) hold partials of head hh
    float ss = ssum;
    ss += __shfl_xor(ss, 8);
    ss += __shfl_xor(ss, 16);
    ss += __shfl_xor(ss, 32);
    float inv = 1.f / ss;  // this lane's head = hh
    const int gbase = lane & 56;
#pragma unroll
    for (int h = 0; h < 8; ++h) {
        float invh = __shfl(inv, gbase | h);
        ushort4 o;
        o.x = pack1(acc[h][0] * invh);
        o.y = pack1(acc[h][1] * invh);
        o.z = pack1(acc[h][2] * invh);
        o.w = pack1(acc[h][3] * invh);
        *(ushort4*)(hrow + h * 256) = o;
    }
}

// ---------------- out[n, h*64+d] = sum_k hb[n,h,k] * Wt[h,d,k]  (bf16 MFMA) ----------------

__global__ __launch_bounds__(256) void out_gemm_kernel(const short* __restrict__ hb,
                                                       const short* __restrict__ Wt,
                                                       float* __restrict__ out, int M) {
    const int t = threadIdx.x;
    const int lane = t & 63, wv = t >> 6;
    const int by = blockIdx.y;               // head
    const int n0 = blockIdx.x * 64 + wv * 16;
    const int r = lane & 15;
    const int kg = lane >> 4;                // 0..3
    const int arow = min(n0 + r, M - 1);
    const short* aptr = hb + (size_t)arow * 2048 + by * IN_FEATS + kg * 8;
    const short* bptr = Wt + ((size_t)by * 64 + r) * IN_FEATS + kg * 8;
    f32x4 acc[4];
#pragma unroll
    for (int c = 0; c < 4; ++c) acc[c] = (f32x4){0.f, 0.f, 0.f, 0.f};
#pragma unroll
    for (int kk = 0; kk < IN_FEATS; kk += 32) {
        bf16x8 a = *(const bf16x8*)(aptr + kk);
#pragma unroll
        for (int c = 0; c < 4; ++c) {
            bf16x8 b = *(const bf16x8*)(bptr + (size_t)c * 16 * IN_FEATS + kk);
            acc[c] = __builtin_amdgcn_mfma_f32_16x16x32_bf16(a, b, acc[c], 0, 0, 0);
        }
    }
    const int orow0 = n0 + kg * 4;
#pragma unroll
    for (int c = 0; c < 4; ++c) {
#pragma unroll
        for (int i = 0; i < 4; ++i) {
            int rr = orow0 + i;
            if (rr < M) out[(size_t)rr * HD + by * 64 + c * 16 + r] = acc[c][i];
        }
    }
}

// ---------------- launch ----------------

extern "C" void kernel_launch(void* const* d_in, const int* in_sizes, int n_in,
                              void* d_out, int out_size, void* d_ws, size_t ws_size,
                              hipStream_t stream) {
    const float* feat   = (const float*)d_in[0];
    const float* W      = (const float*)d_in[1];
    const float* attn_l = (const float*)d_in[2];
    const float* attn_r = (const float*)d_in[3];
    const float* adj    = (const float*)d_in[4];
    const int*   src    = (const int*)d_in[5];
    const int*   dst    = (const int*)d_in[6];
    const int*   idxp   = (const int*)d_in[7];
    float* out = (float*)d_out;

    const int M = in_sizes[0] / IN_FEATS;  // 10000
    const int E = in_sizes[5];             // 320000

    char* ws = (char*)d_ws;
    size_t off = 0;
    auto alloc = [&](size_t bytes) -> void* {
        off = (off + 255) & ~(size_t)255;
        void* p = ws + off;
        off += bytes;
        return p;
    };
    unsigned short* hbuf  = (unsigned short*)alloc((size_t)M * 2048 * sizeof(short));
    unsigned short* featb = (unsigned short*)alloc((size_t)M * IN_FEATS * sizeof(short));
    unsigned short* Wt    = (unsigned short*)alloc((size_t)HD * IN_FEATS * sizeof(short));
    float* wlr       = (float*)alloc((size_t)IN_FEATS * 16 * sizeof(float));
    float* el        = (float*)alloc((size_t)M * NUM_HEADS * sizeof(float));
    float* er        = (float*)alloc((size_t)M * NUM_HEADS * sizeof(float));
    int*   deg       = (int*)alloc((size_t)M * sizeof(int));
    int*   row_start = (int*)alloc((size_t)(M + 1) * sizeof(int));
    int*   cursor    = (int*)alloc((size_t)M * sizeof(int));
    int*   slot_src  = (int*)alloc((size_t)E * sizeof(int));

    hipMemsetAsync(deg, 0, (size_t)M * sizeof(int), stream);

    const int nb_cnt = (E + 255) / 256;            // 1250
    const int nb_wlr = IN_FEATS / 4;               // 64
    k1_kernel<<<nb_cnt + 32 + nb_wlr, 256, 0, stream>>>(W, attn_l, attn_r, dst, deg,
                                                        wlr, Wt, E, nb_cnt);
    scan_kernel<<<1, 1024, 0, stream>>>(deg, row_start, cursor, M);
    const int nb_elr = (M + 3) / 4;                // 2500
    k3_kernel<<<nb_cnt + nb_elr, 256, 0, stream>>>(src, dst, cursor, slot_src,
                                                   feat, wlr, el, er, featb, E, M, nb_cnt);
    agg_kernel<<<(M + 3) / 4, 256, 0, stream>>>(featb, el, er, adj, row_start,
                                                slot_src, idxp, hbuf, M);
    dim3 og((M + 63) / 64, NUM_HEADS);
    out_gemm_kernel<<<og, 256, 0, stream>>>((const short*)hbuf, (const short*)Wt, out, M);
}